// Round 1
// baseline (1598.733 us; speedup 1.0000x reference)
//
#include <hip/hip_runtime.h>
#include <hip/hip_bf16.h>

#define NQ 8
#define NC 1024
#define DD 128
#define BB 16
#define SS 2048
#define RR (BB * SS)   // 32768 rows
#define GAMMA_F 0.99f

// ---------------------------------------------------------------- transpose in
// res[b*SS+s][d] = data[b][d][s]
__global__ __launch_bounds__(256) void k_transpose_in(
    const float* __restrict__ data, float* __restrict__ res)
{
  __shared__ float tile[32][33];
  int b = blockIdx.z;
  int s0 = blockIdx.x << 5, d0 = blockIdx.y << 5;
  int tx = threadIdx.x, ty = threadIdx.y;   // (32,8)
  #pragma unroll
  for (int r = 0; r < 32; r += 8)
    tile[ty + r][tx] = data[((size_t)b * DD + d0 + ty + r) * SS + s0 + tx];
  __syncthreads();
  #pragma unroll
  for (int r = 0; r < 32; r += 8)
    res[((size_t)b * SS + s0 + ty + r) * DD + d0 + tx] = tile[tx][ty + r];
}

// ---------------------------------------------------------------- ||W||^2
__global__ void k_wsq(const float* __restrict__ W, float* __restrict__ wsq)
{
  int c = blockIdx.x * blockDim.x + threadIdx.x;
  if (c >= NQ * NC) return;
  const float4* p = reinterpret_cast<const float4*>(W + (size_t)c * DD);
  float s = 0.f;
  #pragma unroll 8
  for (int k = 0; k < DD / 4; ++k) {
    float4 v = p[k];
    s += v.x * v.x + v.y * v.y + v.z * v.z + v.w * v.w;
  }
  wsq[c] = s;
}

// ---------------------------------------------------------------- argmin GEMM
// 128 rows/block, all 1024 codes in 8 tiles of 128. 512 threads.
// micro-tile: 8 rows x 4 codes per thread. XOR-swizzled LDS (float4 granules).
#define BR 128
#define BC 128
__global__ __launch_bounds__(512) void k_argmin(
    const float* __restrict__ res, const float* __restrict__ W,
    const float* __restrict__ wsq, int* __restrict__ idx_out,
    float* __restrict__ idxf_out, int stage)
{
  __shared__ float Rt[BR * DD];   // 64 KiB
  __shared__ float Wt[BC * DD];   // 64 KiB
  float4* R4 = reinterpret_cast<float4*>(Rt);
  float4* W4 = reinterpret_cast<float4*>(Wt);
  const int t = threadIdx.x;
  const int row0 = blockIdx.x * BR;
  const float* Ws = W + (size_t)stage * NC * DD;
  const float* wsqs = wsq + stage * NC;

  const float4* gres = reinterpret_cast<const float4*>(res + (size_t)row0 * DD);
  #pragma unroll
  for (int it = 0; it < 8; ++it) {
    int fi = it * 512 + t;
    int row = fi >> 5, c4 = fi & 31;
    R4[row * 32 + (c4 ^ (row & 15))] = gres[row * 32 + c4];
  }

  const int tr = t >> 5;   // 0..15 -> rows tr*8 .. tr*8+7
  const int tc = t & 31;   // codes tc + 32*j

  float best[8];
  int bidx[8];
  #pragma unroll
  for (int i = 0; i < 8; ++i) { best[i] = 3.4e38f; bidx[i] = 0; }

  for (int ct = 0; ct < NC / BC; ++ct) {
    __syncthreads();
    const float4* gw = reinterpret_cast<const float4*>(Ws + (size_t)ct * BC * DD);
    #pragma unroll
    for (int it = 0; it < 8; ++it) {
      int fi = it * 512 + t;
      int row = fi >> 5, c4 = fi & 31;
      W4[row * 32 + (c4 ^ (row & 15))] = gw[row * 32 + c4];
    }
    __syncthreads();

    float acc[8][4];
    #pragma unroll
    for (int i = 0; i < 8; ++i)
      #pragma unroll
      for (int j = 0; j < 4; ++j) acc[i][j] = 0.f;

    #pragma unroll 4
    for (int k4 = 0; k4 < DD / 4; ++k4) {
      float4 a[8], bv[4];
      #pragma unroll
      for (int i = 0; i < 8; ++i) {
        int row = tr * 8 + i;
        a[i] = R4[row * 32 + (k4 ^ (row & 15))];
      }
      #pragma unroll
      for (int j = 0; j < 4; ++j) {
        int row = tc + 32 * j;
        bv[j] = W4[row * 32 + (k4 ^ (row & 15))];
      }
      #pragma unroll
      for (int i = 0; i < 8; ++i)
        #pragma unroll
        for (int j = 0; j < 4; ++j) {
          acc[i][j] = fmaf(a[i].x, bv[j].x, acc[i][j]);
          acc[i][j] = fmaf(a[i].y, bv[j].y, acc[i][j]);
          acc[i][j] = fmaf(a[i].z, bv[j].z, acc[i][j]);
          acc[i][j] = fmaf(a[i].w, bv[j].w, acc[i][j]);
        }
    }

    #pragma unroll
    for (int j = 0; j < 4; ++j) {
      int code = ct * BC + tc + 32 * j;
      float sq = wsqs[code];
      #pragma unroll
      for (int i = 0; i < 8; ++i) {
        float v = fmaf(-2.f, acc[i][j], sq);   // ||W||^2 - 2 r.W
        if (v < best[i]) { best[i] = v; bidx[i] = code; }
      }
    }
  }

  // reduce across the 32 tc-lanes (same tr = contiguous lanes, xor stays inside)
  #pragma unroll
  for (int m = 1; m < 32; m <<= 1) {
    #pragma unroll
    for (int i = 0; i < 8; ++i) {
      float ov = __shfl_xor(best[i], m);
      int oi = __shfl_xor(bidx[i], m);
      if (ov < best[i] || (ov == best[i] && oi < bidx[i])) { best[i] = ov; bidx[i] = oi; }
    }
  }
  if (tc == 0) {
    #pragma unroll
    for (int i = 0; i < 8; ++i) {
      int row = row0 + tr * 8 + i;
      idx_out[row] = bidx[i];
      idxf_out[row] = (float)bidx[i];
    }
  }
}

// ---------------------------------------------------------------- per-row update
__global__ __launch_bounds__(256) void k_update(
    const float* __restrict__ res_cur, float* __restrict__ res_next,
    const float* __restrict__ W, const int* __restrict__ idx,
    float* __restrict__ counts, float* __restrict__ sums, int stage)
{
  int row = blockIdx.x * 2 + (threadIdx.x >> 7);
  int d = threadIdx.x & 127;
  int id = idx[row];
  size_t ro = (size_t)row * DD + d;
  float r = res_cur[ro];
  float q = W[((size_t)stage * NC + id) * DD + d];
  res_next[ro] = r - q;
  atomicAdd(&sums[(size_t)id * DD + d], r);
  if (d == 0) atomicAdd(&counts[id], 1.0f);
}

// ---------------------------------------------------------------- threefry2x32 (JAX-exact)
__device__ __forceinline__ unsigned rotl32(unsigned v, int r) { return (v << r) | (v >> (32 - r)); }

__device__ void threefry2x32(unsigned ks0, unsigned ks1, unsigned x0, unsigned x1,
                             unsigned& o0, unsigned& o1)
{
  unsigned ks2 = ks0 ^ ks1 ^ 0x1BD11BDAu;
  x0 += ks0; x1 += ks1;
  // group 1: 13,15,26,6
  x0 += x1; x1 = rotl32(x1, 13); x1 ^= x0;
  x0 += x1; x1 = rotl32(x1, 15); x1 ^= x0;
  x0 += x1; x1 = rotl32(x1, 26); x1 ^= x0;
  x0 += x1; x1 = rotl32(x1, 6);  x1 ^= x0;
  x0 += ks1; x1 += ks2 + 1u;
  // group 2: 17,29,16,24
  x0 += x1; x1 = rotl32(x1, 17); x1 ^= x0;
  x0 += x1; x1 = rotl32(x1, 29); x1 ^= x0;
  x0 += x1; x1 = rotl32(x1, 16); x1 ^= x0;
  x0 += x1; x1 = rotl32(x1, 24); x1 ^= x0;
  x0 += ks2; x1 += ks0 + 2u;
  // group 3: 13,15,26,6
  x0 += x1; x1 = rotl32(x1, 13); x1 ^= x0;
  x0 += x1; x1 = rotl32(x1, 15); x1 ^= x0;
  x0 += x1; x1 = rotl32(x1, 26); x1 ^= x0;
  x0 += x1; x1 = rotl32(x1, 6);  x1 ^= x0;
  x0 += ks0; x1 += ks1 + 3u;
  // group 4: 17,29,16,24
  x0 += x1; x1 = rotl32(x1, 17); x1 ^= x0;
  x0 += x1; x1 = rotl32(x1, 29); x1 ^= x0;
  x0 += x1; x1 = rotl32(x1, 16); x1 ^= x0;
  x0 += x1; x1 = rotl32(x1, 24); x1 ^= x0;
  x0 += ks1; x1 += ks2 + 4u;
  // group 5: 13,15,26,6
  x0 += x1; x1 = rotl32(x1, 13); x1 ^= x0;
  x0 += x1; x1 = rotl32(x1, 15); x1 ^= x0;
  x0 += x1; x1 = rotl32(x1, 26); x1 ^= x0;
  x0 += x1; x1 = rotl32(x1, 6);  x1 ^= x0;
  x0 += ks2; x1 += ks0 + 5u;
  o0 = x0; o1 = x1;
}

// ---------------------------------------------------------------- EMA / dead codes
__global__ __launch_bounds__(128) void k_finalize(
    const float* __restrict__ Ni_in, const float* __restrict__ mi_in,
    const float* __restrict__ counts, const float* __restrict__ sums,
    const float* __restrict__ res_cur,
    float* __restrict__ outNi, float* __restrict__ outmi, float* __restrict__ outW,
    int stage)
{
  const float ONEMG = (float)(1.0 - 0.99);
  int c = blockIdx.x, d = threadIdx.x;
  float cnt = counts[c];
  float ni = Ni_in[stage * NC + c] * GAMMA_F + cnt * ONEMG;
  float m = mi_in[((size_t)stage * NC + c) * DD + d] * GAMMA_F
          + sums[(size_t)c * DD + d] * ONEMG;
  float w = m / fmaxf(ni, 1e-8f);
  if (ni < 2.0f) {
    // rid = randint(fold_in(key(42), stage), (1024,), 0, 32768)[c]
    unsigned K0, K1, a0, a1, b0, b1, o0, o1;
    threefry2x32(0u, 42u, 0u, (unsigned)stage, K0, K1);   // fold_in
    threefry2x32(K0, K1, 0u, 2u, a0, a1);                 // split: counts (0,2),(1,3)
    threefry2x32(K0, K1, 1u, 3u, b0, b1);
    // k2 = second row of split = (a1, b1); lower_bits = random_bits(k2, 32, 1024)
    unsigned bits;
    if (c < 512) { threefry2x32(a1, b1, (unsigned)c, (unsigned)(c + 512), o0, o1); bits = o0; }
    else         { threefry2x32(a1, b1, (unsigned)(c - 512), (unsigned)c, o0, o1); bits = o1; }
    int rid = (int)(bits & 32767u);
    w = res_cur[(size_t)rid * DD + d];
  }
  if (d == 0) outNi[stage * NC + c] = ni;
  size_t o = ((size_t)stage * NC + c) * DD + d;
  outmi[o] = m;
  outW[o] = w;
}

// ---------------------------------------------------------------- logits + loss
__global__ __launch_bounds__(256) void k_final(
    const float* __restrict__ data, const float* __restrict__ res,
    float* __restrict__ logits, float* __restrict__ loss)
{
  __shared__ float tile[32][33];
  int b = blockIdx.z, s0 = blockIdx.x << 5, d0 = blockIdx.y << 5;
  int tx = threadIdx.x, ty = threadIdx.y;
  #pragma unroll
  for (int r = 0; r < 32; r += 8)
    tile[ty + r][tx] = res[((size_t)b * SS + s0 + ty + r) * DD + d0 + tx];
  __syncthreads();
  float l = 0.f;
  #pragma unroll
  for (int r = 0; r < 32; r += 8) {
    int dv = d0 + ty + r, s = s0 + tx;
    size_t o = ((size_t)b * DD + dv) * SS + s;
    float rv = tile[tx][ty + r];
    logits[o] = data[o] - rv;         // == cur_y_t up to rounding
    l = fmaf(rv, rv, l);
  }
  #pragma unroll
  for (int m = 1; m < 64; m <<= 1) l += __shfl_xor(l, m);
  int lin = ty * 32 + tx;
  if ((lin & 63) == 0) atomicAdd(loss, l * (1.0f / 4194304.0f));
}

// ---------------------------------------------------------------- launch
extern "C" void kernel_launch(void* const* d_in, const int* in_sizes, int n_in,
                              void* d_out, int out_size, void* d_ws, size_t ws_size,
                              hipStream_t stream)
{
  (void)in_sizes; (void)n_in; (void)out_size; (void)ws_size;
  const float* data = (const float*)d_in[0];
  const float* W    = (const float*)d_in[1];
  const float* Ni   = (const float*)d_in[2];
  const float* mi   = (const float*)d_in[3];

  float* out        = (float*)d_out;
  float* out_logits = out;
  float* out_loss   = out + (size_t)BB * DD * SS;       // 4194304
  float* out_idx    = out_loss + 1;
  float* out_Ni     = out_idx + (size_t)NQ * RR;        // +262144
  float* out_mi     = out_Ni + (size_t)NQ * NC;         // +8192
  float* out_W      = out_mi + (size_t)NQ * NC * DD;    // +1048576

  float* resA   = (float*)d_ws;
  float* resB   = resA + (size_t)RR * DD;
  int*   idxw   = (int*)(resB + (size_t)RR * DD);
  float* counts = (float*)(idxw + RR);
  float* sums   = counts + NC;
  float* wsq    = sums + (size_t)NC * DD;

  k_transpose_in<<<dim3(SS / 32, DD / 32, BB), dim3(32, 8), 0, stream>>>(data, resA);
  k_wsq<<<(NQ * NC + 255) / 256, 256, 0, stream>>>(W, wsq);

  float* cur = resA;
  float* nxt = resB;
  for (int i = 0; i < NQ; ++i) {
    hipMemsetAsync(counts, 0, (NC + (size_t)NC * DD) * sizeof(float), stream);
    k_argmin<<<RR / BR, 512, 0, stream>>>(cur, W, wsq, idxw, out_idx + (size_t)i * RR, i);
    k_update<<<RR / 2, 256, 0, stream>>>(cur, nxt, W, idxw, counts, sums, i);
    k_finalize<<<NC, 128, 0, stream>>>(Ni, mi, counts, sums, cur, out_Ni, out_mi, out_W, i);
    float* tmp = cur; cur = nxt; nxt = tmp;
  }

  hipMemsetAsync(out_loss, 0, sizeof(float), stream);
  k_final<<<dim3(SS / 32, DD / 32, BB), dim3(32, 8), 0, stream>>>(data, cur, out_logits, out_loss);
}